// Round 3
// baseline (296.230 us; speedup 1.0000x reference)
//
#include <hip/hip_runtime.h>

#define NC 19
#define NB 10
#define NCELL (NC * NB)            // 190
#define NPART (3 * NCELL + 2 * NC) // 608: conf[190] pred[190] acc[190] psum[19] inval[19]
#define REP 4
#define NSLOT 16                   // global accumulator replicas (atomic-chain spreading)
#define BLOCKS 2048
#define TPB 256

// ---------------------------------------------------------------------------
// Pass 1: per-pixel softmax + binned accumulation.
// 2 pixels/thread via float2 (8B/lane), 20 independent loads issued up front,
// tile sized to stay in VGPRs (~38 for logits + 19 psum). 2048 blocks for
// occupancy/MLP. LDS histogram with REP=4 replicas (lane&3).
// Bin-0 (~87% of entries) is NOT atomically accumulated: recovered in pass2:
//   pred(c,0) = valid(c) - sum_{b>=1} pred(c,b)
//   conf(c,0) = psum(c)  - sum_{b>=1} conf(c,b)
// ---------------------------------------------------------------------------
__global__ __launch_bounds__(TPB) void cce_pass1(
    const float* __restrict__ logits, const int* __restrict__ tgt,
    float* __restrict__ gacc, int hw)
{
    constexpr int O_CONF = 0;
    constexpr int O_PRED = REP * NCELL;                // 760
    constexpr int O_ACC  = 2 * REP * NCELL;            // 1520
    constexpr int O_PSUM = 3 * REP * NCELL;            // 2280
    constexpr int O_INV  = 3 * REP * NCELL + REP * NC; // 2356
    constexpr int LDS_N  = O_INV + NC;                 // 2375 floats = 9.5 KB

    __shared__ float lds[LDS_N];
    for (int i = threadIdx.x; i < LDS_N; i += TPB) lds[i] = 0.0f;
    __syncthreads();

    const int rep = threadIdx.x & (REP - 1);
    float psum[NC];
#pragma unroll
    for (int c = 0; c < NC; ++c) psum[c] = 0.0f;

    const int ngroups  = hw >> 1;                      // float2 groups
    const int tid      = blockIdx.x * TPB + threadIdx.x;
    const int nthreads = gridDim.x * TPB;

    for (int g = tid; g < ngroups; g += nthreads) {
        // --- 20 independent loads, all issued before any use ---
        float xa[NC], xb[NC];
#pragma unroll
        for (int c = 0; c < NC; ++c) {
            const float2 v = *reinterpret_cast<const float2*>(
                logits + (size_t)c * hw + 2 * (size_t)g);
            xa[c] = v.x; xb[c] = v.y;
        }
        const int2 t2 = *reinterpret_cast<const int2*>(tgt + 2 * (size_t)g);

        float m0 = xa[0], m1 = xb[0];
#pragma unroll
        for (int c = 1; c < NC; ++c) { m0 = fmaxf(m0, xa[c]); m1 = fmaxf(m1, xb[c]); }

        float s0 = 0.0f, s1 = 0.0f;
#pragma unroll
        for (int c = 0; c < NC; ++c) {
            xa[c] = __expf(xa[c] - m0); s0 += xa[c];   // native v_exp_f32
            xb[c] = __expf(xb[c] - m1); s1 += xb[c];
        }
        const float r0 = __builtin_amdgcn_rcpf(s0);
        const float r1 = __builtin_amdgcn_rcpf(s1);

        float pt0 = 0.0f, pt1 = 0.0f, pmin0 = 1.0f, pmin1 = 1.0f;
#pragma unroll
        for (int c = 0; c < NC; ++c) {
            const float p0 = xa[c] * r0;
            const float p1 = xb[c] * r1;
            psum[c] += p0 + p1;
            if (c == t2.x) pt0 = p0;                   // cndmask, c is imm
            if (c == t2.y) pt1 = p1;
            pmin0 = fminf(pmin0, p0);
            pmin1 = fminf(pmin1, p1);
            const float q0 = p0 * 10.0f, q1 = p1 * 10.0f;
            if (q0 > 1.0f) {                           // bin >= 1
                int b = (int)ceilf(q0) - 1; b = b > NB - 1 ? NB - 1 : b;
                atomicAdd(&lds[O_CONF + rep * NCELL + c * NB + b], p0);
                atomicAdd(&lds[O_PRED + rep * NCELL + c * NB + b], 1.0f);
            }
            if (q1 > 1.0f) {
                int b = (int)ceilf(q1) - 1; b = b > NB - 1 ? NB - 1 : b;
                atomicAdd(&lds[O_CONF + rep * NCELL + c * NB + b], p1);
                atomicAdd(&lds[O_PRED + rep * NCELL + c * NB + b], 1.0f);
            }
        }
        if (pt0 > 0.0f) {                              // no_acc: 1 atomic/pixel
            int b = (int)ceilf(pt0 * 10.0f) - 1;
            b = b < 0 ? 0 : (b > NB - 1 ? NB - 1 : b);
            atomicAdd(&lds[O_ACC + rep * NCELL + t2.x * NB + b], 1.0f);
        }
        if (pt1 > 0.0f) {
            int b = (int)ceilf(pt1 * 10.0f) - 1;
            b = b < 0 ? 0 : (b > NB - 1 ? NB - 1 : b);
            atomicAdd(&lds[O_ACC + rep * NCELL + t2.y * NB + b], 1.0f);
        }
        // ultra-rare underflow path (one branch per pixel, not 19)
        if (!(pmin0 > 0.0f)) {
#pragma unroll
            for (int c = 0; c < NC; ++c)
                if (!(xa[c] * r0 > 0.0f)) atomicAdd(&lds[O_INV + c], 1.0f);
        }
        if (!(pmin1 > 0.0f)) {
#pragma unroll
            for (int c = 0; c < NC; ++c)
                if (!(xb[c] * r1 > 0.0f)) atomicAdd(&lds[O_INV + c], 1.0f);
        }
    }
#pragma unroll
    for (int c = 0; c < NC; ++c)
        atomicAdd(&lds[O_PSUM + rep * NC + c], psum[c]);
    __syncthreads();

    // Reduce replicas; spread block flushes over NSLOT global accumulator sets.
    float* slot = gacc + (size_t)(blockIdx.x & (NSLOT - 1)) * NPART;
    for (int j = threadIdx.x; j < NPART; j += TPB) {
        float v = 0.0f;
        if (j < NCELL) {
            for (int r = 0; r < REP; ++r) v += lds[O_CONF + r * NCELL + j];
        } else if (j < 2 * NCELL) {
            for (int r = 0; r < REP; ++r) v += lds[O_PRED + r * NCELL + (j - NCELL)];
        } else if (j < 3 * NCELL) {
            for (int r = 0; r < REP; ++r) v += lds[O_ACC + r * NCELL + (j - 2 * NCELL)];
        } else if (j < 3 * NCELL + NC) {
            for (int r = 0; r < REP; ++r) v += lds[O_PSUM + r * NC + (j - 3 * NCELL)];
        } else {
            v = lds[O_INV + (j - 3 * NCELL - NC)];
        }
        atomicAdd(&slot[j], v);
    }
}

// ---------------------------------------------------------------------------
// Pass 2: sum NSLOT slots, bin-0 corrections, 190-cell loss (double).
// slot layout: [0,190) conf, [190,380) pred, [380,570) acc, [570,589) psum,
//              [589,608) inval.
// ---------------------------------------------------------------------------
__global__ void cce_pass2(const float* __restrict__ gacc, float* __restrict__ out, int hw)
{
    __shared__ double fin[NPART];
    const int j = threadIdx.x; // blockDim = 640
    if (j < NPART) {
        double v = 0.0;
        for (int s = 0; s < NSLOT; ++s) v += (double)gacc[(size_t)s * NPART + j];
        fin[j] = v;
    }
    __syncthreads();

    if (j < NC) {
        double spred = 0.0, sconf = 0.0;
        for (int b = 1; b < NB; ++b) {
            spred += fin[NCELL + j * NB + b];
            sconf += fin[j * NB + b];
        }
        const double validc = (double)hw - fin[3 * NCELL + NC + j];
        fin[NCELL + j * NB] = validc - spred;             // pred(c,0)
        fin[j * NB]         = fin[3 * NCELL + j] - sconf; // conf(c,0)
    }
    __syncthreads();

    if (j < 64) {
        double tot = 0.0;
        for (int c = j; c < NCELL; c += 64) tot += fin[NCELL + c];
#pragma unroll
        for (int o = 32; o > 0; o >>= 1) tot += __shfl_down(tot, o);
        tot = __shfl(tot, 0);

        double loss = 0.0;
        for (int c = j; c < NCELL; c += 64) {
            const double pred = fin[NCELL + c];
            const double conf = fin[c];
            const double acc  = fin[2 * NCELL + c];
            const double d    = (acc - conf) / (pred + 1e-13);
            loss += d * d * (pred / tot);
        }
#pragma unroll
        for (int o = 32; o > 0; o >>= 1) loss += __shfl_down(loss, o);
        if (j == 0) out[0] = (float)loss;
    }
}

extern "C" void kernel_launch(void* const* d_in, const int* in_sizes, int n_in,
                              void* d_out, int out_size, void* d_ws, size_t ws_size,
                              hipStream_t stream)
{
    const float* logits = (const float*)d_in[0];
    const int*   tgt    = (const int*)d_in[1];
    float*       gacc   = (float*)d_ws;
    const int    hw     = in_sizes[1]; // 1024*2048

    hipMemsetAsync(gacc, 0, (size_t)NSLOT * NPART * sizeof(float), stream);
    cce_pass1<<<BLOCKS, TPB, 0, stream>>>(logits, tgt, gacc, hw);
    cce_pass2<<<1, 640, 0, stream>>>(gacc, (float*)d_out, hw);
}

// Round 4
// 271.565 us; speedup vs baseline: 1.0908x; 1.0908x over previous
//
#include <hip/hip_runtime.h>

#define NC 19
#define NB 10
#define NCELL (NC * NB)            // 190
#define NPART (3 * NCELL + 2 * NC) // 608: conf[190] pred[190] acc[190] psum[19] inval[19]
#define REP 4
#define NSLOT 16                   // global accumulator replicas
#define TPB 256
#define TILE 256                   // pixels per tile (1 KB per class row)
#define NROWS (NC + 1)             // 19 class rows + 1 target row
#define BLOCKS 768                 // 3 blocks/CU (LDS-limited)

// global -> LDS direct (16B/lane). LDS dest is wave-uniform; HW adds lane*16.
__device__ __forceinline__ void load16_lds(const void* g, void* l) {
    auto* gp = reinterpret_cast<const unsigned int __attribute__((address_space(1)))*>(
        reinterpret_cast<uintptr_t>(g));
    auto* lp = reinterpret_cast<unsigned int __attribute__((address_space(3)))*>(
        reinterpret_cast<uintptr_t>(l));
    __builtin_amdgcn_global_load_lds(gp, lp, 16, 0, 0);
}

// ---------------------------------------------------------------------------
// Pass 1: LDS-staged softmax + binned accumulation.
// Tile = 256 px. Stage: 20 rows x 1KB, one global_load_lds_dwordx4 each,
// 5 per wave (4 waves). Double-buffered, counted vmcnt(5), raw s_barrier.
// MLP comes from the async LDS-load queue, NOT from VGPRs -> immune to the
// register-allocator load-sinking that killed rounds 1-3.
// Bin-0 (~87% of entries) recovered in pass2 by subtraction:
//   pred(c,0) = valid(c) - sum_{b>=1} pred(c,b)
//   conf(c,0) = psum(c)  - sum_{b>=1} conf(c,b)
// ---------------------------------------------------------------------------
__global__ __launch_bounds__(TPB, 3) void cce_pass1(
    const float* __restrict__ logits, const int* __restrict__ tgt,
    float* __restrict__ gacc, int hw)
{
    constexpr int O_CONF = 0;
    constexpr int O_PRED = REP * NCELL;                // 760
    constexpr int O_ACC  = 2 * REP * NCELL;            // 1520
    constexpr int O_PSUM = 3 * REP * NCELL;            // 2280
    constexpr int O_INV  = 3 * REP * NCELL + REP * NC; // 2356
    constexpr int LDS_N  = O_INV + NC;                 // 2375 floats = 9.5 KB

    __shared__ float buf[2][NROWS][TILE];              // 40 KB
    __shared__ float hist[LDS_N];                      // 9.5 KB

    for (int i = threadIdx.x; i < LDS_N; i += TPB) hist[i] = 0.0f;
    __syncthreads();                                   // also drains vmcnt -> 0

    const int lane = threadIdx.x & 63;
    const int wv   = threadIdx.x >> 6;                 // 0..3
    const int rep  = threadIdx.x & (REP - 1);
    const int p    = threadIdx.x;                      // pixel within tile

    float psum[NC];
#pragma unroll
    for (int c = 0; c < NC; ++c) psum[c] = 0.0f;

    const int ntiles = hw / TILE;                      // 8192 (hw % TILE == 0)
    const int stride = (int)gridDim.x;

    auto stage = [&](int b, int t) {
#pragma unroll
        for (int r5 = 0; r5 < 5; ++r5) {
            const int row = wv * 5 + r5;               // wave-uniform, 0..19
            const void* g = (row < NC)
                ? (const void*)(logits + (size_t)row * hw + (size_t)t * TILE + lane * 4)
                : (const void*)(tgt + (size_t)t * TILE + lane * 4);
            load16_lds(g, (void*)&buf[b][row][0]);
        }
    };

    const int t0 = (int)blockIdx.x;
    if (t0 < ntiles) stage(0, t0);
    int cur = 0;

    for (int t = t0; t < ntiles; t += stride) {
        const int nxt = t + stride;
        if (nxt < ntiles) {
            stage(cur ^ 1, nxt);                       // 5 more in flight (10 total)
            asm volatile("s_waitcnt vmcnt(5)" ::: "memory"); // oldest 5 (tile t) done
        } else {
            asm volatile("s_waitcnt vmcnt(0)" ::: "memory");
        }
        __builtin_amdgcn_s_barrier();                  // all waves: tile t staged
        asm volatile("" ::: "memory");

        float x[NC];
#pragma unroll
        for (int c = 0; c < NC; ++c) x[c] = buf[cur][c][p];
        const int tg = ((const int*)&buf[cur][NC][0])[p];

        float m = x[0];
#pragma unroll
        for (int c = 1; c < NC; ++c) m = fmaxf(m, x[c]);
        float s = 0.0f;
#pragma unroll
        for (int c = 0; c < NC; ++c) { x[c] = __expf(x[c] - m); s += x[c]; }
        const float r = __builtin_amdgcn_rcpf(s);

        float pt = 0.0f, pmin = 1.0f;
#pragma unroll
        for (int c = 0; c < NC; ++c) {
            const float pv = x[c] * r;
            psum[c] += pv;
            if (c == tg) pt = pv;                      // cndmask (c is imm)
            pmin = fminf(pmin, pv);
            const float q = pv * 10.0f;
            if (q > 1.0f) {                            // bin >= 1 only (~13%)
                int bb = (int)ceilf(q) - 1; bb = bb > NB - 1 ? NB - 1 : bb;
                atomicAdd(&hist[O_CONF + rep * NCELL + c * NB + bb], pv);
                atomicAdd(&hist[O_PRED + rep * NCELL + c * NB + bb], 1.0f);
            }
        }
        if (pt > 0.0f) {                               // no_acc: 1 atomic/pixel
            int bb = (int)ceilf(pt * 10.0f) - 1;
            bb = bb < 0 ? 0 : (bb > NB - 1 ? NB - 1 : bb);
            atomicAdd(&hist[O_ACC + rep * NCELL + tg * NB + bb], 1.0f);
        }
        if (!(pmin > 0.0f)) {                          // ultra-rare underflow
#pragma unroll
            for (int c = 0; c < NC; ++c)
                if (!(x[c] * r > 0.0f)) atomicAdd(&hist[O_INV + c], 1.0f);
        }

        asm volatile("" ::: "memory");
        __builtin_amdgcn_s_barrier();                  // buf[cur] free for restage
        cur ^= 1;
    }

#pragma unroll
    for (int c = 0; c < NC; ++c)
        atomicAdd(&hist[O_PSUM + rep * NC + c], psum[c]);
    __syncthreads();

    // Reduce replicas; spread block flushes over NSLOT global accumulator sets.
    float* slot = gacc + (size_t)(blockIdx.x & (NSLOT - 1)) * NPART;
    for (int j = threadIdx.x; j < NPART; j += TPB) {
        float v = 0.0f;
        if (j < NCELL) {
            for (int rr = 0; rr < REP; ++rr) v += hist[O_CONF + rr * NCELL + j];
        } else if (j < 2 * NCELL) {
            for (int rr = 0; rr < REP; ++rr) v += hist[O_PRED + rr * NCELL + (j - NCELL)];
        } else if (j < 3 * NCELL) {
            for (int rr = 0; rr < REP; ++rr) v += hist[O_ACC + rr * NCELL + (j - 2 * NCELL)];
        } else if (j < 3 * NCELL + NC) {
            for (int rr = 0; rr < REP; ++rr) v += hist[O_PSUM + rr * NC + (j - 3 * NCELL)];
        } else {
            v = hist[O_INV + (j - 3 * NCELL - NC)];
        }
        atomicAdd(&slot[j], v);
    }
}

// ---------------------------------------------------------------------------
// Pass 2: sum NSLOT slots, bin-0 corrections, 190-cell loss (double).
// ---------------------------------------------------------------------------
__global__ void cce_pass2(const float* __restrict__ gacc, float* __restrict__ out, int hw)
{
    __shared__ double fin[NPART];
    const int j = threadIdx.x; // blockDim = 640
    if (j < NPART) {
        double v = 0.0;
        for (int s = 0; s < NSLOT; ++s) v += (double)gacc[(size_t)s * NPART + j];
        fin[j] = v;
    }
    __syncthreads();

    if (j < NC) {
        double spred = 0.0, sconf = 0.0;
        for (int b = 1; b < NB; ++b) {
            spred += fin[NCELL + j * NB + b];
            sconf += fin[j * NB + b];
        }
        const double validc = (double)hw - fin[3 * NCELL + NC + j];
        fin[NCELL + j * NB] = validc - spred;             // pred(c,0)
        fin[j * NB]         = fin[3 * NCELL + j] - sconf; // conf(c,0)
    }
    __syncthreads();

    if (j < 64) {
        double tot = 0.0;
        for (int c = j; c < NCELL; c += 64) tot += fin[NCELL + c];
#pragma unroll
        for (int o = 32; o > 0; o >>= 1) tot += __shfl_down(tot, o);
        tot = __shfl(tot, 0);

        double loss = 0.0;
        for (int c = j; c < NCELL; c += 64) {
            const double pred = fin[NCELL + c];
            const double conf = fin[c];
            const double acc  = fin[2 * NCELL + c];
            const double d    = (acc - conf) / (pred + 1e-13);
            loss += d * d * (pred / tot);
        }
#pragma unroll
        for (int o = 32; o > 0; o >>= 1) loss += __shfl_down(loss, o);
        if (j == 0) out[0] = (float)loss;
    }
}

extern "C" void kernel_launch(void* const* d_in, const int* in_sizes, int n_in,
                              void* d_out, int out_size, void* d_ws, size_t ws_size,
                              hipStream_t stream)
{
    const float* logits = (const float*)d_in[0];
    const int*   tgt    = (const int*)d_in[1];
    float*       gacc   = (float*)d_ws;
    const int    hw     = in_sizes[1]; // 1024*2048

    hipMemsetAsync(gacc, 0, (size_t)NSLOT * NPART * sizeof(float), stream);
    cce_pass1<<<BLOCKS, TPB, 0, stream>>>(logits, tgt, gacc, hw);
    cce_pass2<<<1, 640, 0, stream>>>(gacc, (float*)d_out, hw);
}